// Round 23
// baseline (71.680 us; speedup 1.0000x reference)
//
#include <hip/hip_runtime.h>
#include <hip/hip_bf16.h>
#include <cmath>

#define BDIM 8
#define HDIM 256
#define LDIM 4096
#define NDIM 64
#define TCH  64
#define NCH  64

typedef unsigned short u16;
typedef unsigned int   u32;
typedef __attribute__((ext_vector_type(8))) short short8x;
typedef __attribute__((ext_vector_type(4))) float f32x4;

__device__ __forceinline__ float rcp_fast(float x) { return __builtin_amdgcn_rcpf(x); }
__device__ __forceinline__ float tanh_fast(float x) {
    float e = __expf(2.0f * x);
    return 1.0f - 2.0f * rcp_fast(e + 1.0f);
}
__device__ __forceinline__ u16 f2bf(float f) {
    unsigned int u = __float_as_uint(f);
    u = u + 0x7fffu + ((u >> 16) & 1u);
    return (u16)(u >> 16);
}
__device__ __forceinline__ float bf2f(u16 s) {
    return __uint_as_float(((unsigned int)s) << 16);
}

// ---------------------------------------------------------------------------
// tables6: G,T,P single-bf16; P dump coalesced via LDS; fused prep_w.
// ---------------------------------------------------------------------------
__global__ __launch_bounds__(256) void tables6_kernel(
    const float* __restrict__ lre_g, const float* __restrict__ lim_g,
    const float* __restrict__ cbre_g, const float* __restrict__ cbim_g,
    const float* __restrict__ W,
    u16* __restrict__ Phi,
    u16* __restrict__ Ghi, u16* __restrict__ Thi,
    float2* __restrict__ L64,
    u16* __restrict__ Wphi)
{
    __shared__ float qre[64][64];   // [t][n]
    __shared__ float qim[64][64];
    __shared__ float Ksh[64];
    const int h = blockIdx.x;
    const int tid = threadIdx.x;
    const int w = tid >> 6;                 // t-block 0..3
    const int n = tid & 63;

    const float lr = lre_g[h * 64 + n], li = lim_g[h * 64 + n];
    const float cr = 2.0f * cbre_g[h * 64 + n];
    const float ci = 2.0f * cbim_g[h * 64 + n];

    u32* Gh32 = (u32*)(Ghi + (size_t)h * 8192);
    u16* Th = Thi + (size_t)h * 4096;

    // ---- fused prep_w: rows 2h (a: W[h]) and 2h+1 (g: W[h+256]) ----
    Wphi[(2 * h) * 256 + tid]     = f2bf(W[h * 256 + tid]);
    Wphi[(2 * h + 1) * 256 + tid] = f2bf(W[(h + 256) * 256 + tid]);

    // s = Lam^16
    float sr = lr, si = li;
    #pragma unroll
    for (int j = 0; j < 4; ++j) {
        float tr = sr * sr - si * si;
        si = 2.0f * sr * si; sr = tr;
    }
    // q = Lam^{16w}
    float qr = 1.0f, qi = 0.0f;
    for (int j = 0; j < w; ++j) {
        float tr = qr * sr - qi * si;
        qi = qr * si + qi * sr; qr = tr;
    }

    #pragma unroll
    for (int j = 0; j < 16; ++j) {
        const int t = 16 * w + j;
        float kp = cr * qr - ci * qi;                // 2Re(CB Lam^t)
        #pragma unroll
        for (int m = 32; m > 0; m >>= 1) kp += __shfl_xor(kp, m);
        if (n == 0) Ksh[t] = kp;

        qre[t][n] = qr; qim[t][n] = qi;              // Lam^t -> LDS

        float nqr = qr * lr - qi * li;               // Lam^{t+1}
        float nqi = qr * li + qi * lr;
        qr = nqr; qi = nqi;

        float gre = cr * qr - ci * qi;               // 2Re(CB Lam^{t+1})
        float gnim = -(cr * qi + ci * qr);           // -2Im(...)
        Gh32[t * 64 + n] = (u32)f2bf(gre) | ((u32)f2bf(gnim) << 16);
    }
    if (w == 3) L64[h * 64 + n] = make_float2(qr, qi);   // Lam^64
    __syncthreads();

    // ---- P dump (coalesced, single bf16) ----
    {
        const int row = tid >> 1;
        const int n0  = row >> 1;
        const float* src = (row & 1) ? &qim[0][0] : &qre[0][0];
        const int s0 = (tid & 1) * 32;
        union { u16 s[32]; short8x v[4]; } HB;
        #pragma unroll
        for (int i = 0; i < 32; ++i) {
            int s = s0 + i;
            HB.s[i] = f2bf(src[(63 - s) * 64 + n0]); // Lam^{63-s}
        }
        u16* dh = Phi + (size_t)h * 8192 + row * 64 + s0;
        #pragma unroll
        for (int k2 = 0; k2 < 4; ++k2)
            *(short8x*)(dh + 8 * k2) = HB.v[k2];
    }

    // ---- T build (single bf16) ----
    const int r = tid >> 2, c0 = (tid & 3) * 16;
    #pragma unroll
    for (int i = 0; i < 16; ++i) {
        int c = c0 + i;
        float val = (c <= r) ? Ksh[r - c] : 0.0f;
        Th[r * 64 + c] = f2bf(val);
    }
}

// ---------------------------------------------------------------------------
// scan5k: scan5j + s_setprio(1) around MFMA clusters (T5: independent
// blocks at different phases -> scheduler favors MFMA waves) + epilogue u
// prefetch issued BEFORE the Y MFMA cluster.
// LDS 69 rows x 512 B = 35328 B. 3 barriers. y bf16 to ws.
// ---------------------------------------------------------------------------
__global__ __launch_bounds__(256, 4) void scan5k_kernel(
    const float* __restrict__ u,
    const float* __restrict__ Dg,
    const u16* __restrict__ Phi,
    const u16* __restrict__ Ghi, const u16* __restrict__ Thi,
    const float2* __restrict__ L64,
    u16* __restrict__ ybf)
{
    __shared__ __align__(16) char smem[69 * 512];

    const int bid = blockIdx.x;
    const int b = bid >> 8;
    const int h = ((bid >> 3) & 31) * 8 + (bid & 7);   // same-h blocks share an XCD
    const int tid = threadIdx.x;
    const int w = tid >> 6, l = tid & 63;
    const int l15 = l & 15, lhi = l >> 4;

    const int ctBase  = (w & 1) * 2;
    const int miBaseV = (w >> 1) * 4;
    const int miBaseY = (w >> 1) * 2;

    const float* urow = u + ((size_t)b * HDIM + h) * LDIM;

    // ---- U B-fragments (single bf16), direct from global ----
    int cBt[2];
    short8x ub[2][2];                                  // [ct2][ks]
    #pragma unroll
    for (int ct2 = 0; ct2 < 2; ++ct2) {
        cBt[ct2] = 16 * (ctBase + ct2) + l15;
        #pragma unroll
        for (int ks = 0; ks < 2; ++ks) {
            const float* src = urow + 64 * cBt[ct2] + 32 * ks + 8 * lhi;
            float4 f0 = *(const float4*)src;
            float4 f1 = *(const float4*)(src + 4);
            float fv[8] = {f0.x, f0.y, f0.z, f0.w, f1.x, f1.y, f1.z, f1.w};
            union { short8x v; u16 s[8]; } H;
            #pragma unroll
            for (int q = 0; q < 8; ++q) H.s[q] = f2bf(fv[q]);
            ub[ct2][ks] = H.v;
        }
    }

    // ---- V = P x U : 4 mi x 2 ct per wave ----
    const u16* Ph = Phi + (size_t)h * 8192;
    {
        f32x4 acc[4][2];
        #pragma unroll
        for (int m = 0; m < 4; ++m)
            #pragma unroll
            for (int c2 = 0; c2 < 2; ++c2)
                acc[m][c2] = (f32x4){0.0f, 0.0f, 0.0f, 0.0f};

        #pragma unroll
        for (int pair = 0; pair < 2; ++pair) {
            short8x pah[2][2];                         // [m][ks]
            #pragma unroll
            for (int m = 0; m < 2; ++m)
                #pragma unroll
                for (int ks = 0; ks < 2; ++ks) {
                    int off = (16 * (miBaseV + 2 * pair + m) + l15) * 64 + 32 * ks + 8 * lhi;
                    pah[m][ks] = *(const short8x*)(Ph + off);
                }
            __builtin_amdgcn_s_setprio(1);
            #pragma unroll
            for (int m = 0; m < 2; ++m)
                #pragma unroll
                for (int ks = 0; ks < 2; ++ks)
                    #pragma unroll
                    for (int c2 = 0; c2 < 2; ++c2) {
                        acc[2 * pair + m][c2] = __builtin_amdgcn_mfma_f32_16x16x32_bf16(
                            pah[m][ks], ub[c2][ks], acc[2 * pair + m][c2], 0, 0, 0);
                    }
            __builtin_amdgcn_s_setprio(0);
        }
        #pragma unroll
        for (int m = 0; m < 4; ++m)
            #pragma unroll
            for (int c2 = 0; c2 < 2; ++c2) {
                int rV = cBt[c2] + 1;
                int byte = 512 * rV + 64 * (miBaseV + m) + 16 * lhi;
                *(f32x4*)(smem + (byte ^ ((rV & 7) << 4))) = acc[m][c2];
            }
    }

    // ---- T x U partial (scan-independent): folded into Y after B3 ----
    const u16* Th_ = Thi + (size_t)h * 4096;
    f32x4 accTU[2][2];                                 // [m][c2]
    {
        short8x tah[2][2];                             // [m][ks]
        #pragma unroll
        for (int m = 0; m < 2; ++m)
            #pragma unroll
            for (int ks = 0; ks < 2; ++ks) {
                int off = (16 * (miBaseY + m) + l15) * 64 + 32 * ks + 8 * lhi;
                tah[m][ks] = *(const short8x*)(Th_ + off);
            }
        __builtin_amdgcn_s_setprio(1);
        #pragma unroll
        for (int m = 0; m < 2; ++m)
            #pragma unroll
            for (int c2 = 0; c2 < 2; ++c2) {
                f32x4 a = {0.0f, 0.0f, 0.0f, 0.0f};
                #pragma unroll
                for (int ks = 0; ks < 2; ++ks)
                    a = __builtin_amdgcn_mfma_f32_16x16x32_bf16(tah[m][ks], ub[c2][ks], a, 0, 0, 0);
                accTU[m][c2] = a;
            }
        __builtin_amdgcn_s_setprio(0);
    }
    __syncthreads();                                   // B1: V complete

    // ---- prefetch BOTH mi's G fragments (ride out the chunk-scan) ----
    const u16* Gh_ = Ghi + (size_t)h * 8192;
    short8x gah_pf[2][4];
    #pragma unroll
    for (int m = 0; m < 2; ++m)
        #pragma unroll
        for (int ks = 0; ks < 4; ++ks) {
            int off = (16 * (miBaseY + m) + l15) * 128 + 32 * ks + 8 * lhi;
            gah_pf[m][ks] = *(const short8x*)(Gh_ + off);
        }

    // ---- PARALLEL chunk-scan: wave g handles chunks 16g..16g+15, lane = n ----
    {
        const int g = w, a = 16 * g;
        float2 lt = L64[h * 64 + l];                   // Lam^64 per lane
        float2 vv[16];
        #pragma unroll
        for (int j = 0; j < 16; ++j) {
            int r = a + j + 1;
            vv[j] = *(const float2*)(smem + ((512 * r + 8 * l) ^ ((r & 7) << 4)));
        }
        float ljr[16], lji[16];
        float xr = 0.0f, xi = 0.0f;
        #pragma unroll
        for (int j = 0; j < 16; ++j) {
            ljr[j] = xr; lji[j] = xi;
            float nr = fmaf(lt.x, xr, fmaf(-lt.y, xi, vv[j].x));
            float ni = fmaf(lt.x, xi, fmaf( lt.y, xr, vv[j].y));
            xr = nr; xi = ni;
        }
        {
            int r = 65 + g;
            *(float2*)(smem + ((512 * r + 8 * l) ^ ((r & 7) << 4))) = make_float2(xr, xi);
        }
        float p16r = lt.x, p16i = lt.y;
        #pragma unroll
        for (int jj = 0; jj < 4; ++jj) {
            float tr = p16r * p16r - p16i * p16i;
            p16i = 2.0f * p16r * p16i; p16r = tr;
        }
        __syncthreads();                               // B2: totals ready
        float sr = 0.0f, si = 0.0f;
        for (int gp = 0; gp < g; ++gp) {
            int r = 65 + gp;
            float2 t = *(const float2*)(smem + ((512 * r + 8 * l) ^ ((r & 7) << 4)));
            float nsr = fmaf(p16r, sr, fmaf(-p16i, si, t.x));
            float nsi = fmaf(p16r, si, fmaf( p16i, sr, t.y));
            sr = nsr; si = nsi;
        }
        float pr = 1.0f, pi = 0.0f;
        #pragma unroll
        for (int j = 0; j < 16; ++j) {
            float Xr = fmaf(pr, sr, fmaf(-pi, si, ljr[j]));
            float Xi = fmaf(pr, si, fmaf( pi, sr, lji[j]));
            int c = a + j, sw2 = (c & 7) << 4;
            *(u32*)(smem + ((512 * c + 4 * l) ^ sw2)) =
                (u32)f2bf(Xr) | ((u32)f2bf(Xi) << 16);
            float npr = pr * lt.x - pi * lt.y;
            float npi = pr * lt.y + pi * lt.x;
            pr = npr; pi = npi;
        }
    }
    __syncthreads();                                   // B3: all X written (LDS read-only after)

    // ---- X B-frags into regs (single bf16) + epilogue u prefetch ----
    short8x xb[2][4];                                  // [ct2][ks]
    #pragma unroll
    for (int c2 = 0; c2 < 2; ++c2) {
        int swX = (cBt[c2] & 7) << 4;
        #pragma unroll
        for (int ks = 0; ks < 4; ++ks) {
            int byte = 512 * cBt[c2] + 64 * ks + 16 * lhi;
            xb[c2][ks] = *(const short8x*)(smem + (byte ^ swX));
        }
    }
    float4 upf[2][2];                                  // [m][c2] epilogue u
    #pragma unroll
    for (int m = 0; m < 2; ++m)
        #pragma unroll
        for (int c2 = 0; c2 < 2; ++c2)
            upf[m][c2] = *(const float4*)(urow + 64 * cBt[c2] + 16 * (miBaseY + m) + 4 * lhi);

    // ---- Y = G x X + accTU : direct C-fragment epilogue ----
    const float Dh = Dg[h];
    u16* yrow = ybf + ((size_t)b * HDIM + h) * LDIM;
    #pragma unroll
    for (int m = 0; m < 2; ++m) {
        const int mi = miBaseY + m;
        f32x4 acc[2];
        acc[0] = accTU[m][0];
        acc[1] = accTU[m][1];
        __builtin_amdgcn_s_setprio(1);
        #pragma unroll
        for (int ks = 0; ks < 4; ++ks)
            #pragma unroll
            for (int c2 = 0; c2 < 2; ++c2)
                acc[c2] = __builtin_amdgcn_mfma_f32_16x16x32_bf16(
                    gah_pf[m][ks], xb[c2][ks], acc[c2], 0, 0, 0);
        __builtin_amdgcn_s_setprio(0);
        #pragma unroll
        for (int c2 = 0; c2 < 2; ++c2) {
            int off = 64 * cBt[c2] + 16 * mi + 4 * lhi;
            float4 uv = upf[m][c2];
            float o0 = tanh_fast(fmaf(Dh, uv.x, acc[c2][0]));
            float o1 = tanh_fast(fmaf(Dh, uv.y, acc[c2][1]));
            float o2 = tanh_fast(fmaf(Dh, uv.z, acc[c2][2]));
            float o3 = tanh_fast(fmaf(Dh, uv.w, acc[c2][3]));
            uint2 pk;
            pk.x = (u32)f2bf(o0) | ((u32)f2bf(o1) << 16);
            pk.y = (u32)f2bf(o2) | ((u32)f2bf(o3) << 16);
            *(uint2*)(yrow + off) = pk;                // 8B store, aligned
        }
    }
}

// ---------------------------------------------------------------------------
// mix13 (r16/r19 measured best): BM=256 x BN=128 row-split, 512 threads /
// 8 waves, K=256 in 4 steps, double-buffered. Grid 32 x 2 x 8 = 512 blocks.
// ---------------------------------------------------------------------------
__global__ __launch_bounds__(512, 2) void mix13_kernel(
    const u16* __restrict__ ybf,           // [B][256][4096] bf16
    const u16* __restrict__ Wphi,
    const float* __restrict__ bm,
    float* __restrict__ out)               // d_out f32
{
    __shared__ __align__(16) u16 Ysh[2][128 * 64];   // 2 x 16 KB

    const int tid = threadIdx.x;
    const int w = tid >> 6, l = tid & 63;
    const int l15 = l & 15, lhi = l >> 4;
    const int rbase = blockIdx.y * 256;    // row half
    const int b = blockIdx.z;
    const int col0 = blockIdx.x * 128;

    const u16* Yb = ybf + (size_t)b * HDIM * LDIM;

    const int p  = tid >> 4;               // k-pair 0..31
    const int cg = tid & 15;               // col-group of 8

    f32x4 acc[2][8];                       // [mi][ct]
    #pragma unroll
    for (int mi = 0; mi < 2; ++mi)
        #pragma unroll
        for (int ct = 0; ct < 8; ++ct)
            acc[mi][ct] = (f32x4){0.0f, 0.0f, 0.0f, 0.0f};

    // ---- prologue: stage kb=0 into buf 0 ----
    {
        const u16* r0 = Yb + (size_t)(2 * p) * LDIM + col0 + 8 * cg;
        union { short8x v; u16 s[8]; } Y0, Y1;
        Y0.v = *(const short8x*)r0;
        Y1.v = *(const short8x*)(r0 + LDIM);
        #pragma unroll
        for (int q = 0; q < 8; ++q) {
            int col = 8 * cg + q;
            u32 wv = (u32)Y0.s[q] | ((u32)Y1.s[q] << 16);
            int byte = (col * 128 + 4 * p) ^ ((col & 7) << 4);
            *(u32*)((char*)Ysh[0] + byte) = wv;
        }
    }
    __syncthreads();

    for (int kb = 0; kb < 4; ++kb) {
        const int k0 = kb * 64;
        const int cur = kb & 1;

        union { short8x v; u16 s[8]; } Y0, Y1;
        if (kb < 3) {
            const u16* r0 = Yb + (size_t)(k0 + 64 + 2 * p) * LDIM + col0 + 8 * cg;
            Y0.v = *(const short8x*)r0;
            Y1.v = *(const short8x*)(r0 + LDIM);
        }

        #pragma unroll
        for (int mi = 0; mi < 2; ++mi) {
            const size_t row = (size_t)(rbase + 32 * w + 16 * mi + l15);
            short8x wh[2];
            #pragma unroll
            for (int ks = 0; ks < 2; ++ks) {
                size_t off = row * 256 + k0 + 32 * ks + 8 * lhi;
                wh[ks] = *(const short8x*)(Wphi + off);
            }
            #pragma unroll
            for (int ct = 0; ct < 8; ++ct) {
                #pragma unroll
                for (int ks = 0; ks < 2; ++ks) {
                    int col = 16 * ct + l15;
                    int byte = (col * 128 + 64 * ks + 16 * lhi) ^ ((col & 7) << 4);
                    short8x yb = *(const short8x*)((char*)Ysh[cur] + byte);
                    acc[mi][ct] = __builtin_amdgcn_mfma_f32_16x16x32_bf16(wh[ks], yb, acc[mi][ct], 0, 0, 0);
                }
            }
        }

        if (kb < 3) {
            #pragma unroll
            for (int q = 0; q < 8; ++q) {
                int col = 8 * cg + q;
                u32 wv = (u32)Y0.s[q] | ((u32)Y1.s[q] << 16);
                int byte = (col * 128 + 4 * p) ^ ((col & 7) << 4);
                *(u32*)((char*)Ysh[cur ^ 1] + byte) = wv;
            }
        }
        __syncthreads();
    }

    // ---- epilogue: bias + GLU + store ----
    float* ob = out + ((size_t)b * HDIM) * LDIM;
    #pragma unroll
    for (int mi = 0; mi < 2; ++mi) {
        int r0 = rbase + 32 * w + 16 * mi + 4 * lhi;   // multiple of 4
        int h1 = r0 >> 1;
        float ba1 = bm[h1],     bg1 = bm[h1 + 256];
        float ba2 = bm[h1 + 1], bg2 = bm[h1 + 1 + 256];
        #pragma unroll
        for (int ct = 0; ct < 8; ++ct) {
            f32x4 a = acc[mi][ct];
            int col = col0 + 16 * ct + l15;
            float A1 = a[0] + ba1, G1 = a[1] + bg1;
            float A2 = a[2] + ba2, G2 = a[3] + bg2;
            ob[(size_t)h1 * LDIM + col]       = A1 * rcp_fast(1.0f + __expf(-G1));
            ob[(size_t)(h1 + 1) * LDIM + col] = A2 * rcp_fast(1.0f + __expf(-G2));
        }
    }
}

// ---------------------------------------------------------------------------
extern "C" void kernel_launch(void* const* d_in, const int* in_sizes, int n_in,
                              void* d_out, int out_size, void* d_ws, size_t ws_size,
                              hipStream_t stream)
{
    const float* u    = (const float*)d_in[0];
    const float* lre  = (const float*)d_in[1];
    const float* lim  = (const float*)d_in[2];
    const float* cbre = (const float*)d_in[3];
    const float* cbim = (const float*)d_in[4];
    const float* Dg   = (const float*)d_in[5];
    const float* W    = (const float*)d_in[6];
    const float* bm   = (const float*)d_in[7];
    float* out = (float*)d_out;

    char* ws = (char*)d_ws;
    size_t o = 0;
    u16* Wphi = (u16*)(ws + o); o += (size_t)1 << 19;      // 512 KB (256 used)
    u16* Phi = (u16*)(ws + o); o += (size_t)1 << 22;       // 4 MB
    u16* Ghi = (u16*)(ws + o); o += (size_t)1 << 22;       // 4 MB
    u16* Thi = (u16*)(ws + o); o += (size_t)1 << 21;       // 2 MB
    float2* L64 = (float2*)(ws + o); o += (size_t)1 << 18; // 256 KB (128 used)
    u16* ybf = (u16*)(ws + o);                             // 16.78 MB

    tables6_kernel<<<HDIM, 256, 0, stream>>>(lre, lim, cbre, cbim, W,
                                             Phi, Ghi, Thi, L64, Wphi);
    scan5k_kernel<<<BDIM * HDIM, 256, 0, stream>>>(u, Dg, Phi, Ghi,
                                                   Thi, L64, ybf);
    dim3 grid(LDIM / 128, 2, BDIM);
    mix13_kernel<<<grid, 512, 0, stream>>>(ybf, Wphi, bm, out);
}

// Round 24
// 71.015 us; speedup vs baseline: 1.0094x; 1.0094x over previous
//
#include <hip/hip_runtime.h>
#include <hip/hip_bf16.h>
#include <cmath>

#define BDIM 8
#define HDIM 256
#define LDIM 4096
#define NDIM 64
#define TCH  64
#define NCH  64

typedef unsigned short u16;
typedef unsigned int   u32;
typedef __attribute__((ext_vector_type(8))) short short8x;
typedef __attribute__((ext_vector_type(4))) float f32x4;

__device__ __forceinline__ float rcp_fast(float x) { return __builtin_amdgcn_rcpf(x); }
__device__ __forceinline__ float tanh_fast(float x) {
    float e = __expf(2.0f * x);
    return 1.0f - 2.0f * rcp_fast(e + 1.0f);
}
__device__ __forceinline__ u16 f2bf(float f) {
    unsigned int u = __float_as_uint(f);
    u = u + 0x7fffu + ((u >> 16) & 1u);
    return (u16)(u >> 16);
}
__device__ __forceinline__ float bf2f(u16 s) {
    return __uint_as_float(((unsigned int)s) << 16);
}

// ---------------------------------------------------------------------------
// tables6: G,T,P single-bf16; P dump coalesced via LDS; fused prep_w.
// ---------------------------------------------------------------------------
__global__ __launch_bounds__(256) void tables6_kernel(
    const float* __restrict__ lre_g, const float* __restrict__ lim_g,
    const float* __restrict__ cbre_g, const float* __restrict__ cbim_g,
    const float* __restrict__ W,
    u16* __restrict__ Phi,
    u16* __restrict__ Ghi, u16* __restrict__ Thi,
    float2* __restrict__ L64,
    u16* __restrict__ Wphi)
{
    __shared__ float qre[64][64];   // [t][n]
    __shared__ float qim[64][64];
    __shared__ float Ksh[64];
    const int h = blockIdx.x;
    const int tid = threadIdx.x;
    const int w = tid >> 6;                 // t-block 0..3
    const int n = tid & 63;

    const float lr = lre_g[h * 64 + n], li = lim_g[h * 64 + n];
    const float cr = 2.0f * cbre_g[h * 64 + n];
    const float ci = 2.0f * cbim_g[h * 64 + n];

    u32* Gh32 = (u32*)(Ghi + (size_t)h * 8192);
    u16* Th = Thi + (size_t)h * 4096;

    // ---- fused prep_w: rows 2h (a: W[h]) and 2h+1 (g: W[h+256]) ----
    Wphi[(2 * h) * 256 + tid]     = f2bf(W[h * 256 + tid]);
    Wphi[(2 * h + 1) * 256 + tid] = f2bf(W[(h + 256) * 256 + tid]);

    // s = Lam^16
    float sr = lr, si = li;
    #pragma unroll
    for (int j = 0; j < 4; ++j) {
        float tr = sr * sr - si * si;
        si = 2.0f * sr * si; sr = tr;
    }
    // q = Lam^{16w}
    float qr = 1.0f, qi = 0.0f;
    for (int j = 0; j < w; ++j) {
        float tr = qr * sr - qi * si;
        qi = qr * si + qi * sr; qr = tr;
    }

    #pragma unroll
    for (int j = 0; j < 16; ++j) {
        const int t = 16 * w + j;
        float kp = cr * qr - ci * qi;                // 2Re(CB Lam^t)
        #pragma unroll
        for (int m = 32; m > 0; m >>= 1) kp += __shfl_xor(kp, m);
        if (n == 0) Ksh[t] = kp;

        qre[t][n] = qr; qim[t][n] = qi;              // Lam^t -> LDS

        float nqr = qr * lr - qi * li;               // Lam^{t+1}
        float nqi = qr * li + qi * lr;
        qr = nqr; qi = nqi;

        float gre = cr * qr - ci * qi;               // 2Re(CB Lam^{t+1})
        float gnim = -(cr * qi + ci * qr);           // -2Im(...)
        Gh32[t * 64 + n] = (u32)f2bf(gre) | ((u32)f2bf(gnim) << 16);
    }
    if (w == 3) L64[h * 64 + n] = make_float2(qr, qi);   // Lam^64
    __syncthreads();

    // ---- P dump (coalesced, single bf16) ----
    {
        const int row = tid >> 1;
        const int n0  = row >> 1;
        const float* src = (row & 1) ? &qim[0][0] : &qre[0][0];
        const int s0 = (tid & 1) * 32;
        union { u16 s[32]; short8x v[4]; } HB;
        #pragma unroll
        for (int i = 0; i < 32; ++i) {
            int s = s0 + i;
            HB.s[i] = f2bf(src[(63 - s) * 64 + n0]); // Lam^{63-s}
        }
        u16* dh = Phi + (size_t)h * 8192 + row * 64 + s0;
        #pragma unroll
        for (int k2 = 0; k2 < 4; ++k2)
            *(short8x*)(dh + 8 * k2) = HB.v[k2];
    }

    // ---- T build (single bf16) ----
    const int r = tid >> 2, c0 = (tid & 3) * 16;
    #pragma unroll
    for (int i = 0; i < 16; ++i) {
        int c = c0 + i;
        float val = (c <= r) ? Ksh[r - c] : 0.0f;
        Th[r * 64 + c] = f2bf(val);
    }
}

// ---------------------------------------------------------------------------
// scan5j (r19/r22 measured best): all operands single-bf16, T*U hoisted
// pre-B1, both G frags prefetched post-B1, direct C-fragment epilogue,
// y bf16 to ws. LDS 69 rows x 512 B = 35328 B. 3 barriers.
// ---------------------------------------------------------------------------
__global__ __launch_bounds__(256, 4) void scan5j_kernel(
    const float* __restrict__ u,
    const float* __restrict__ Dg,
    const u16* __restrict__ Phi,
    const u16* __restrict__ Ghi, const u16* __restrict__ Thi,
    const float2* __restrict__ L64,
    u16* __restrict__ ybf)
{
    __shared__ __align__(16) char smem[69 * 512];

    const int bid = blockIdx.x;
    const int b = bid >> 8;
    const int h = ((bid >> 3) & 31) * 8 + (bid & 7);   // same-h blocks share an XCD
    const int tid = threadIdx.x;
    const int w = tid >> 6, l = tid & 63;
    const int l15 = l & 15, lhi = l >> 4;

    const int ctBase  = (w & 1) * 2;
    const int miBaseV = (w >> 1) * 4;
    const int miBaseY = (w >> 1) * 2;

    const float* urow = u + ((size_t)b * HDIM + h) * LDIM;

    // ---- U B-fragments (single bf16), direct from global ----
    int cBt[2];
    short8x ub[2][2];                                  // [ct2][ks]
    #pragma unroll
    for (int ct2 = 0; ct2 < 2; ++ct2) {
        cBt[ct2] = 16 * (ctBase + ct2) + l15;
        #pragma unroll
        for (int ks = 0; ks < 2; ++ks) {
            const float* src = urow + 64 * cBt[ct2] + 32 * ks + 8 * lhi;
            float4 f0 = *(const float4*)src;
            float4 f1 = *(const float4*)(src + 4);
            float fv[8] = {f0.x, f0.y, f0.z, f0.w, f1.x, f1.y, f1.z, f1.w};
            union { short8x v; u16 s[8]; } H;
            #pragma unroll
            for (int q = 0; q < 8; ++q) H.s[q] = f2bf(fv[q]);
            ub[ct2][ks] = H.v;
        }
    }

    // ---- V = P x U : 4 mi x 2 ct per wave ----
    const u16* Ph = Phi + (size_t)h * 8192;
    {
        f32x4 acc[4][2];
        #pragma unroll
        for (int m = 0; m < 4; ++m)
            #pragma unroll
            for (int c2 = 0; c2 < 2; ++c2)
                acc[m][c2] = (f32x4){0.0f, 0.0f, 0.0f, 0.0f};

        #pragma unroll
        for (int pair = 0; pair < 2; ++pair) {
            short8x pah[2][2];                         // [m][ks]
            #pragma unroll
            for (int m = 0; m < 2; ++m)
                #pragma unroll
                for (int ks = 0; ks < 2; ++ks) {
                    int off = (16 * (miBaseV + 2 * pair + m) + l15) * 64 + 32 * ks + 8 * lhi;
                    pah[m][ks] = *(const short8x*)(Ph + off);
                }
            #pragma unroll
            for (int m = 0; m < 2; ++m)
                #pragma unroll
                for (int ks = 0; ks < 2; ++ks)
                    #pragma unroll
                    for (int c2 = 0; c2 < 2; ++c2) {
                        acc[2 * pair + m][c2] = __builtin_amdgcn_mfma_f32_16x16x32_bf16(
                            pah[m][ks], ub[c2][ks], acc[2 * pair + m][c2], 0, 0, 0);
                    }
        }
        #pragma unroll
        for (int m = 0; m < 4; ++m)
            #pragma unroll
            for (int c2 = 0; c2 < 2; ++c2) {
                int rV = cBt[c2] + 1;
                int byte = 512 * rV + 64 * (miBaseV + m) + 16 * lhi;
                *(f32x4*)(smem + (byte ^ ((rV & 7) << 4))) = acc[m][c2];
            }
    }

    // ---- T x U partial (scan-independent): folded into Y after B3 ----
    const u16* Th_ = Thi + (size_t)h * 4096;
    f32x4 accTU[2][2];                                 // [m][c2]
    {
        short8x tah[2][2];                             // [m][ks]
        #pragma unroll
        for (int m = 0; m < 2; ++m)
            #pragma unroll
            for (int ks = 0; ks < 2; ++ks) {
                int off = (16 * (miBaseY + m) + l15) * 64 + 32 * ks + 8 * lhi;
                tah[m][ks] = *(const short8x*)(Th_ + off);
            }
        #pragma unroll
        for (int m = 0; m < 2; ++m)
            #pragma unroll
            for (int c2 = 0; c2 < 2; ++c2) {
                f32x4 a = {0.0f, 0.0f, 0.0f, 0.0f};
                #pragma unroll
                for (int ks = 0; ks < 2; ++ks)
                    a = __builtin_amdgcn_mfma_f32_16x16x32_bf16(tah[m][ks], ub[c2][ks], a, 0, 0, 0);
                accTU[m][c2] = a;
            }
    }
    __syncthreads();                                   // B1: V complete

    // ---- prefetch BOTH mi's G fragments (ride out the chunk-scan) ----
    const u16* Gh_ = Ghi + (size_t)h * 8192;
    short8x gah_pf[2][4];
    #pragma unroll
    for (int m = 0; m < 2; ++m)
        #pragma unroll
        for (int ks = 0; ks < 4; ++ks) {
            int off = (16 * (miBaseY + m) + l15) * 128 + 32 * ks + 8 * lhi;
            gah_pf[m][ks] = *(const short8x*)(Gh_ + off);
        }

    // ---- PARALLEL chunk-scan: wave g handles chunks 16g..16g+15, lane = n ----
    {
        const int g = w, a = 16 * g;
        float2 lt = L64[h * 64 + l];                   // Lam^64 per lane
        float2 vv[16];
        #pragma unroll
        for (int j = 0; j < 16; ++j) {
            int r = a + j + 1;
            vv[j] = *(const float2*)(smem + ((512 * r + 8 * l) ^ ((r & 7) << 4)));
        }
        float ljr[16], lji[16];
        float xr = 0.0f, xi = 0.0f;
        #pragma unroll
        for (int j = 0; j < 16; ++j) {
            ljr[j] = xr; lji[j] = xi;
            float nr = fmaf(lt.x, xr, fmaf(-lt.y, xi, vv[j].x));
            float ni = fmaf(lt.x, xi, fmaf( lt.y, xr, vv[j].y));
            xr = nr; xi = ni;
        }
        {
            int r = 65 + g;
            *(float2*)(smem + ((512 * r + 8 * l) ^ ((r & 7) << 4))) = make_float2(xr, xi);
        }
        float p16r = lt.x, p16i = lt.y;
        #pragma unroll
        for (int jj = 0; jj < 4; ++jj) {
            float tr = p16r * p16r - p16i * p16i;
            p16i = 2.0f * p16r * p16i; p16r = tr;
        }
        __syncthreads();                               // B2: totals ready
        float sr = 0.0f, si = 0.0f;
        for (int gp = 0; gp < g; ++gp) {
            int r = 65 + gp;
            float2 t = *(const float2*)(smem + ((512 * r + 8 * l) ^ ((r & 7) << 4)));
            float nsr = fmaf(p16r, sr, fmaf(-p16i, si, t.x));
            float nsi = fmaf(p16r, si, fmaf( p16i, sr, t.y));
            sr = nsr; si = nsi;
        }
        float pr = 1.0f, pi = 0.0f;
        #pragma unroll
        for (int j = 0; j < 16; ++j) {
            float Xr = fmaf(pr, sr, fmaf(-pi, si, ljr[j]));
            float Xi = fmaf(pr, si, fmaf( pi, sr, lji[j]));
            int c = a + j, sw2 = (c & 7) << 4;
            *(u32*)(smem + ((512 * c + 4 * l) ^ sw2)) =
                (u32)f2bf(Xr) | ((u32)f2bf(Xi) << 16);
            float npr = pr * lt.x - pi * lt.y;
            float npi = pr * lt.y + pi * lt.x;
            pr = npr; pi = npi;
        }
    }
    __syncthreads();                                   // B3: all X written (LDS read-only after)

    // ---- X B-frags into regs (single bf16) ----
    short8x xb[2][4];                                  // [ct2][ks]
    #pragma unroll
    for (int c2 = 0; c2 < 2; ++c2) {
        int swX = (cBt[c2] & 7) << 4;
        #pragma unroll
        for (int ks = 0; ks < 4; ++ks) {
            int byte = 512 * cBt[c2] + 64 * ks + 16 * lhi;
            xb[c2][ks] = *(const short8x*)(smem + (byte ^ swX));
        }
    }

    // ---- Y = G x X + accTU : direct C-fragment epilogue ----
    const float Dh = Dg[h];
    u16* yrow = ybf + ((size_t)b * HDIM + h) * LDIM;
    #pragma unroll
    for (int m = 0; m < 2; ++m) {
        const int mi = miBaseY + m;
        f32x4 acc[2];
        acc[0] = accTU[m][0];
        acc[1] = accTU[m][1];
        #pragma unroll
        for (int ks = 0; ks < 4; ++ks)
            #pragma unroll
            for (int c2 = 0; c2 < 2; ++c2)
                acc[c2] = __builtin_amdgcn_mfma_f32_16x16x32_bf16(
                    gah_pf[m][ks], xb[c2][ks], acc[c2], 0, 0, 0);
        #pragma unroll
        for (int c2 = 0; c2 < 2; ++c2) {
            int off = 64 * cBt[c2] + 16 * mi + 4 * lhi;
            float4 uv = *(const float4*)(urow + off);
            float o0 = tanh_fast(fmaf(Dh, uv.x, acc[c2][0]));
            float o1 = tanh_fast(fmaf(Dh, uv.y, acc[c2][1]));
            float o2 = tanh_fast(fmaf(Dh, uv.z, acc[c2][2]));
            float o3 = tanh_fast(fmaf(Dh, uv.w, acc[c2][3]));
            uint2 pk;
            pk.x = (u32)f2bf(o0) | ((u32)f2bf(o1) << 16);
            pk.y = (u32)f2bf(o2) | ((u32)f2bf(o3) << 16);
            *(uint2*)(yrow + off) = pk;                // 8B store, aligned
        }
    }
}

// ---------------------------------------------------------------------------
// mix13 (r16/r19 measured best): BM=256 x BN=128 row-split, 512 threads /
// 8 waves, K=256 in 4 steps, double-buffered. Grid 32 x 2 x 8 = 512 blocks.
// ---------------------------------------------------------------------------
__global__ __launch_bounds__(512, 2) void mix13_kernel(
    const u16* __restrict__ ybf,           // [B][256][4096] bf16
    const u16* __restrict__ Wphi,
    const float* __restrict__ bm,
    float* __restrict__ out)               // d_out f32
{
    __shared__ __align__(16) u16 Ysh[2][128 * 64];   // 2 x 16 KB

    const int tid = threadIdx.x;
    const int w = tid >> 6, l = tid & 63;
    const int l15 = l & 15, lhi = l >> 4;
    const int rbase = blockIdx.y * 256;    // row half
    const int b = blockIdx.z;
    const int col0 = blockIdx.x * 128;

    const u16* Yb = ybf + (size_t)b * HDIM * LDIM;

    const int p  = tid >> 4;               // k-pair 0..31
    const int cg = tid & 15;               // col-group of 8

    f32x4 acc[2][8];                       // [mi][ct]
    #pragma unroll
    for (int mi = 0; mi < 2; ++mi)
        #pragma unroll
        for (int ct = 0; ct < 8; ++ct)
            acc[mi][ct] = (f32x4){0.0f, 0.0f, 0.0f, 0.0f};

    // ---- prologue: stage kb=0 into buf 0 ----
    {
        const u16* r0 = Yb + (size_t)(2 * p) * LDIM + col0 + 8 * cg;
        union { short8x v; u16 s[8]; } Y0, Y1;
        Y0.v = *(const short8x*)r0;
        Y1.v = *(const short8x*)(r0 + LDIM);
        #pragma unroll
        for (int q = 0; q < 8; ++q) {
            int col = 8 * cg + q;
            u32 wv = (u32)Y0.s[q] | ((u32)Y1.s[q] << 16);
            int byte = (col * 128 + 4 * p) ^ ((col & 7) << 4);
            *(u32*)((char*)Ysh[0] + byte) = wv;
        }
    }
    __syncthreads();

    for (int kb = 0; kb < 4; ++kb) {
        const int k0 = kb * 64;
        const int cur = kb & 1;

        union { short8x v; u16 s[8]; } Y0, Y1;
        if (kb < 3) {
            const u16* r0 = Yb + (size_t)(k0 + 64 + 2 * p) * LDIM + col0 + 8 * cg;
            Y0.v = *(const short8x*)r0;
            Y1.v = *(const short8x*)(r0 + LDIM);
        }

        #pragma unroll
        for (int mi = 0; mi < 2; ++mi) {
            const size_t row = (size_t)(rbase + 32 * w + 16 * mi + l15);
            short8x wh[2];
            #pragma unroll
            for (int ks = 0; ks < 2; ++ks) {
                size_t off = row * 256 + k0 + 32 * ks + 8 * lhi;
                wh[ks] = *(const short8x*)(Wphi + off);
            }
            #pragma unroll
            for (int ct = 0; ct < 8; ++ct) {
                #pragma unroll
                for (int ks = 0; ks < 2; ++ks) {
                    int col = 16 * ct + l15;
                    int byte = (col * 128 + 64 * ks + 16 * lhi) ^ ((col & 7) << 4);
                    short8x yb = *(const short8x*)((char*)Ysh[cur] + byte);
                    acc[mi][ct] = __builtin_amdgcn_mfma_f32_16x16x32_bf16(wh[ks], yb, acc[mi][ct], 0, 0, 0);
                }
            }
        }

        if (kb < 3) {
            #pragma unroll
            for (int q = 0; q < 8; ++q) {
                int col = 8 * cg + q;
                u32 wv = (u32)Y0.s[q] | ((u32)Y1.s[q] << 16);
                int byte = (col * 128 + 4 * p) ^ ((col & 7) << 4);
                *(u32*)((char*)Ysh[cur ^ 1] + byte) = wv;
            }
        }
        __syncthreads();
    }

    // ---- epilogue: bias + GLU + store ----
    float* ob = out + ((size_t)b * HDIM) * LDIM;
    #pragma unroll
    for (int mi = 0; mi < 2; ++mi) {
        int r0 = rbase + 32 * w + 16 * mi + 4 * lhi;   // multiple of 4
        int h1 = r0 >> 1;
        float ba1 = bm[h1],     bg1 = bm[h1 + 256];
        float ba2 = bm[h1 + 1], bg2 = bm[h1 + 1 + 256];
        #pragma unroll
        for (int ct = 0; ct < 8; ++ct) {
            f32x4 a = acc[mi][ct];
            int col = col0 + 16 * ct + l15;
            float A1 = a[0] + ba1, G1 = a[1] + bg1;
            float A2 = a[2] + ba2, G2 = a[3] + bg2;
            ob[(size_t)h1 * LDIM + col]       = A1 * rcp_fast(1.0f + __expf(-G1));
            ob[(size_t)(h1 + 1) * LDIM + col] = A2 * rcp_fast(1.0f + __expf(-G2));
        }
    }
}

// ---------------------------------------------------------------------------
extern "C" void kernel_launch(void* const* d_in, const int* in_sizes, int n_in,
                              void* d_out, int out_size, void* d_ws, size_t ws_size,
                              hipStream_t stream)
{
    const float* u    = (const float*)d_in[0];
    const float* lre  = (const float*)d_in[1];
    const float* lim  = (const float*)d_in[2];
    const float* cbre = (const float*)d_in[3];
    const float* cbim = (const float*)d_in[4];
    const float* Dg   = (const float*)d_in[5];
    const float* W    = (const float*)d_in[6];
    const float* bm   = (const float*)d_in[7];
    float* out = (float*)d_out;

    char* ws = (char*)d_ws;
    size_t o = 0;
    u16* Wphi = (u16*)(ws + o); o += (size_t)1 << 19;      // 512 KB (256 used)
    u16* Phi = (u16*)(ws + o); o += (size_t)1 << 22;       // 4 MB
    u16* Ghi = (u16*)(ws + o); o += (size_t)1 << 22;       // 4 MB
    u16* Thi = (u16*)(ws + o); o += (size_t)1 << 21;       // 2 MB
    float2* L64 = (float2*)(ws + o); o += (size_t)1 << 18; // 256 KB (128 used)
    u16* ybf = (u16*)(ws + o);                             // 16.78 MB

    tables6_kernel<<<HDIM, 256, 0, stream>>>(lre, lim, cbre, cbim, W,
                                             Phi, Ghi, Thi, L64, Wphi);
    scan5j_kernel<<<BDIM * HDIM, 256, 0, stream>>>(u, Dg, Phi, Ghi,
                                                   Thi, L64, ybf);
    dim3 grid(LDIM / 128, 2, BDIM);
    mix13_kernel<<<grid, 512, 0, stream>>>(ybf, Wphi, bm, out);
}